// Round 2
// baseline (416.358 us; speedup 1.0000x reference)
//
#include <hip/hip_runtime.h>

// y[b,c,h,w] = coef[c] * g[b,c,h,w]; g is (32,512,64,64) fp32, coef (512,) fp32.
// (Round-1 NaN proved the buffers are fp32, matching the reference dtypes —
// the harness error-label "bf16" is hardcoded text, not dtype evidence.)
// Memory-bound elementwise: 537 MB total traffic, ~85 us floor at 6.3 TB/s.
// Each thread handles one float4 (16B). H*W = 4096 elems = 1024 float4 per
// channel, so a vector never straddles a channel: c = (vec_idx >> 10) & 511.

__global__ __launch_bounds__(256) void Gradient_28733331210651_kernel(
    const float4* __restrict__ g,
    const float* __restrict__ coef,
    float4* __restrict__ out,
    int nvec)
{
    int i = blockIdx.x * blockDim.x + threadIdx.x;
    if (i >= nvec) return;

    int c = (i >> 10) & 511;        // (4i / 4096) % 512
    float s = coef[c];

    float4 v = g[i];
    float4 r;
    r.x = v.x * s;
    r.y = v.y * s;
    r.z = v.z * s;
    r.w = v.w * s;
    out[i] = r;
}

extern "C" void kernel_launch(void* const* d_in, const int* in_sizes, int n_in,
                              void* d_out, int out_size, void* d_ws, size_t ws_size,
                              hipStream_t stream) {
    const float4* g = (const float4*)d_in[0];
    const float* coef = (const float*)d_in[1];
    float4* out = (float4*)d_out;

    int nvec = in_sizes[0] / 4;             // 67,108,864 / 4 = 16,777,216
    int block = 256;
    int grid = (nvec + block - 1) / block;  // 65536 blocks
    Gradient_28733331210651_kernel<<<grid, block, 0, stream>>>(g, coef, out, nvec);
}

// Round 4
// 413.756 us; speedup vs baseline: 1.0063x; 1.0063x over previous
//
#include <hip/hip_runtime.h>

// y[b,c,h,w] = coef[c] * g[b,c,h,w]; g is (32,512,64,64) fp32, coef (512,) fp32.
// Memory-bound elementwise: 537 MB irreducible traffic -> ~85 us floor at
// ~6.3 TB/s achievable. Round-2 profile: top-5 dispatches are all harness
// re-poison fills (1 GiB @ 166 us, 6.46 TB/s); our kernel absent from top-5
// => kernel < 164 us; dur_us=416 ~= 330 us harness reset + ~85 us kernel.
//
// Round 3 fix: __builtin_nontemporal_* rejects HIP_vector_type float4 —
// use native ext_vector_type(4) float (same global_load_dwordx4 codegen).
//
// H*W = 4096 elems = 1024 float4 per channel, so a 16B vector never straddles
// a channel boundary: c = (vec_idx >> 10) & 511 (wave-uniform: 16 waves/chan).

typedef __attribute__((ext_vector_type(4))) float f32x4;

__global__ __launch_bounds__(256) void Gradient_28733331210651_kernel(
    const f32x4* __restrict__ g,
    const float* __restrict__ coef,
    f32x4* __restrict__ out,
    int nvec)
{
    int stride = gridDim.x * blockDim.x;
    for (int i = blockIdx.x * blockDim.x + threadIdx.x; i < nvec; i += stride) {
        int c = (i >> 10) & 511;        // (4i / 4096) % 512
        float s = coef[c];

        f32x4 v = __builtin_nontemporal_load(&g[i]);
        f32x4 r = v * s;
        __builtin_nontemporal_store(r, &out[i]);
    }
}

extern "C" void kernel_launch(void* const* d_in, const int* in_sizes, int n_in,
                              void* d_out, int out_size, void* d_ws, size_t ws_size,
                              hipStream_t stream) {
    const f32x4* g = (const f32x4*)d_in[0];
    const float* coef = (const float*)d_in[1];
    f32x4* out = (f32x4*)d_out;

    int nvec = in_sizes[0] / 4;   // 67,108,864 / 4 = 16,777,216
    int block = 256;
    int grid = 16384;             // grid-stride: 4 float4 per thread
    Gradient_28733331210651_kernel<<<grid, block, 0, stream>>>(g, coef, out, nvec);
}